// Round 20
// baseline (98.732 us; speedup 1.0000x reference)
//
#include <hip/hip_runtime.h>
#include <hip/hip_bf16.h>
#include <stdint.h>

#define H 128
#define NE 500000
#define NTILES 3907          // ceil(NE/128)
#define TPB 8                // tiles per block -> 489 blocks (2/CU resident)

typedef __bf16 bf16x8 __attribute__((ext_vector_type(8)));
typedef float f32x4 __attribute__((ext_vector_type(4)));

__device__ __forceinline__ float fast_silu(float x) {
    float e = __builtin_amdgcn_exp2f(x * -1.44269504088896341f);
    return x * __builtin_amdgcn_rcpf(1.0f + e);
}

__device__ __forceinline__ unsigned f2bf(float f) {
    unsigned u = __builtin_bit_cast(unsigned, f);
    return (u + 0x7FFFu + ((u >> 16) & 1u)) >> 16;
}

// ---------------------------------------------------------------------------
// Prep: blocks 0..94:  P1[b][c] = emb[b] @ w_lin[0:128][c] + b_lin[c]
//                      P2[b][c] = emb[b] @ w_lin[128:256][c]
//       blocks 95..126: w3t[c][k] = bf16(w_lin[256+k][c]) packed pairs
// ---------------------------------------------------------------------------
__global__ __launch_bounds__(256)
void prep_kernel(const float* __restrict__ emb,
                 const float* __restrict__ w_lin,
                 const float* __restrict__ b_lin,
                 float* __restrict__ P1, float* __restrict__ P2,
                 unsigned* __restrict__ w3t) {
    int b = blockIdx.x, t = threadIdx.x;
    if (b < 95) {
        __shared__ float emb_s[H];
        if (t < H) emb_s[t] = emb[b * H + t];
        __syncthreads();
        int c = t & (H - 1);
        int half = t >> 7;
        const float* wb = w_lin + half * (H * H) + c;
        float a = half ? 0.0f : b_lin[c];
        #pragma unroll 8
        for (int k = 0; k < H; ++k)
            a = fmaf(emb_s[k], wb[k * H], a);
        (half ? P2 : P1)[b * H + c] = a;
    } else {
        int idx = (b - 95) * 256 + t;
        int c = idx >> 6;
        int k = (idx & 63) * 2;
        unsigned lo = f2bf(w_lin[(2 * H + k) * H + c]);
        unsigned hi = f2bf(w_lin[(2 * H + k + 1) * H + c]);
        w3t[idx] = lo | (hi << 16);
    }
}

// ---------------------------------------------------------------------------
// Main: ROUND 20 = r15 champion (82.2us) + two low-risk changes:
//  (1) __launch_bounds__(512, 2): arch-VGPR cap 128 (ledger: cap=256/minwaves;
//      r15 needs ~70-90 -> no spill; LDS already locks 2 blocks/CU so
//      occupancy unchanged at 16 waves/CU).
//  (2) w_rbf/b_rbf staged ONCE per block into LDS (2-way-free 272B/cg
//      layout) -- removes 14 global loads/thread/tile from the h-phase head.
// Everything else identical to r15: NT stores, full __syncthreads,
// wl W3^T in LDS, transpose epilogue, cvt_pk casts.
// ---------------------------------------------------------------------------
__global__ __launch_bounds__(512, 2)
void edge_kernel(const float* __restrict__ rbf,
                 const int* __restrict__ ei, const int* __restrict__ ej,
                 const int* __restrict__ xin,
                 const float* __restrict__ w_rbf, const float* __restrict__ b_rbf,
                 const float* __restrict__ P1, const float* __restrict__ P2,
                 const unsigned* __restrict__ w3t,
                 float* __restrict__ out) {
    __shared__ __align__(16) char hs[H * 256];   // h bf16 tile / f32 staging, 32KB
    __shared__ __align__(16) char wl[H * 256];   // W3^T bf16 swizzled, 32KB
    __shared__ __align__(16) float wr2[16 * 68]; // w_rbf+b_rbf, 272B/colgroup, 4.3KB
    __shared__ float rbf_s[2][128 * 8];          // 2 x 4KB
    __shared__ int xi_s[2][128];
    __shared__ int xj_s[2][128];

    const int tid = threadIdx.x;
    const int wave = tid >> 6;
    const int lane = tid & 63;
    const int we = wave & 3;              // 32-edge group
    const int wc = wave >> 2;             // 64-col group
    const int l15 = lane & 15;
    const int lq = lane >> 4;
    const int c4r = tid & 31;             // readout: 4-col group
    const int erow = tid >> 5;            // readout: edge row 0..15

    const int tile0 = blockIdx.x * TPB;

    // ---------------- stage W3^T -> LDS once per block (swizzled) ----------
    #pragma unroll
    for (int it = 0; it < 16; ++it) {
        int idx = tid + it * 512;          // 0..8191 ; row c = idx>>6
        int c = idx >> 6;
        int b4 = (idx & 63) * 4;
        *(unsigned*)(wl + c * 256 + (b4 ^ ((c & 15) << 4))) = w3t[idx];
    }
    // ---------------- stage w_rbf/b_rbf -> LDS once per block --------------
    // per col-group cg (0..15): k=0..5 at wr2[cg*68 + k*8], bias at +48..55.
    // cg stride 68 dwords -> banks (4*cg)%32 -> 2-way (free, m136).
    #pragma unroll
    for (int it = 0; it < 2; ++it) {
        int d = tid + it * 512;            // 0..895 useful
        if (d < 896) {
            int cg = d / 56, r = d % 56;
            float v = (r < 48) ? w_rbf[(r >> 3) * H + cg * 8 + (r & 7)]
                               : b_rbf[cg * 8 + (r - 48)];
            wr2[cg * 68 + r] = v;
        }
    }

    // ---------------- pipeline registers ----------------
    float pr0 = 0.f, pr1 = 0.f;           // rbf prefetch
    int pidx = 0;                         // raw node index prefetch

    // ---------------- prologue: load + commit tile0 into buf 0 -------------
    {
        long long gb = (long long)tile0 * 768;
        pr0 = (gb + tid < (long long)NE * 6) ? rbf[gb + tid] : 0.f;
        int d1 = tid + 512;
        pr1 = (d1 < 768 && gb + d1 < (long long)NE * 6) ? rbf[gb + d1] : 0.f;
        int e = tile0 * 128 + (tid & 127);
        if (tid < 128)      pidx = (e < NE) ? ei[e] : 0;
        else if (tid < 256) pidx = (e < NE) ? ej[e] : 0;

        int xg = 0;
        if (tid < 256) xg = xin[pidx];
        rbf_s[0][(tid / 6) * 8 + (tid % 6)] = pr0;
        if (tid + 512 < 768) rbf_s[0][((tid + 512) / 6) * 8 + ((tid + 512) % 6)] = pr1;
        if (tid < 128) xi_s[0][tid] = xg;
        else if (tid < 256) xj_s[0][tid - 128] = xg;
    }

    #pragma unroll 1
    for (int t = 0; t < TPB; ++t) {
        const int tile = tile0 + t;
        if (tile >= NTILES) break;
        const int buf = t & 1;
        const bool hn = (t + 1 < TPB) && (tile + 1 < NTILES);

        // ---- issue next tile's global loads early ----
        if (hn) {
            long long gb = (long long)(tile + 1) * 768;
            pr0 = (gb + tid < (long long)NE * 6) ? rbf[gb + tid] : 0.f;
            int d1 = tid + 512;
            pr1 = (d1 < 768 && gb + d1 < (long long)NE * 6) ? rbf[gb + d1] : 0.f;
            int e = (tile + 1) * 128 + (tid & 127);
            if (tid < 128)      pidx = (e < NE) ? ei[e] : 0;
            else if (tid < 256) pidx = (e < NE) ? ej[e] : 0;
        }

        __syncthreads();   // (A) commit + block-staging visible; hs free

        // ---- h-phase: thread owns 8 cols x 4 edges (coeffs from LDS) ----
        {
            const int cg = tid & 15;
            const int eg = tid >> 4;
            const float* wp = wr2 + cg * 68;
            f32x4 w0[6], w1[6];
            #pragma unroll
            for (int k = 0; k < 6; ++k) {
                w0[k] = *(const f32x4*)(wp + k * 8);
                w1[k] = *(const f32x4*)(wp + k * 8 + 4);
            }
            f32x4 b0 = *(const f32x4*)(wp + 48);
            f32x4 b1 = *(const f32x4*)(wp + 52);
            const int c8 = cg * 8;

            #pragma unroll
            for (int i = 0; i < 4; ++i) {
                int el = eg * 4 + i;
                f32x4 r03 = *(const f32x4*)(&rbf_s[buf][el * 8]);
                float2 r45 = *(const float2*)(&rbf_s[buf][el * 8 + 4]);
                float rk[6] = {r03[0], r03[1], r03[2], r03[3], r45.x, r45.y};
                f32x4 s0 = b0, s1 = b1;
                #pragma unroll
                for (int k = 0; k < 6; ++k) {
                    s0 += rk[k] * w0[k];
                    s1 += rk[k] * w1[k];
                }
                bf16x8 hv;
                hv[0] = (__bf16)fast_silu(s0[0]);
                hv[1] = (__bf16)fast_silu(s0[1]);
                hv[2] = (__bf16)fast_silu(s0[2]);
                hv[3] = (__bf16)fast_silu(s0[3]);
                hv[4] = (__bf16)fast_silu(s1[0]);
                hv[5] = (__bf16)fast_silu(s1[1]);
                hv[6] = (__bf16)fast_silu(s1[2]);
                hv[7] = (__bf16)fast_silu(s1[3]);
                *(bf16x8*)(hs + el * 256 + ((c8 * 2) ^ ((el & 15) << 4))) = hv;
            }
        }
        __syncthreads();   // (B) hs (h-tile) ready

        // ---- next tile's xin gather: latency hides under MFMA+epilogue ----
        int xg = 0;
        if (hn && tid < 256) xg = xin[pidx];

        // ---- MFMA: B-fragments from LDS-resident W3^T ----
        f32x4 acc[2][4];
        #pragma unroll
        for (int a = 0; a < 2; ++a)
            #pragma unroll
            for (int b = 0; b < 4; ++b)
                acc[a][b] = (f32x4){0.f, 0.f, 0.f, 0.f};

        #pragma unroll
        for (int ks = 0; ks < 4; ++ks) {
            const int kb = ks * 64 + lq * 16;
            bf16x8 bfr[4];
            #pragma unroll
            for (int cf = 0; cf < 4; ++cf) {
                int c = wc * 64 + cf * 16 + l15;
                bfr[cf] = *(const bf16x8*)(wl + c * 256 + (kb ^ ((c & 15) << 4)));
            }
            bf16x8 afr[2];
            #pragma unroll
            for (int ef = 0; ef < 2; ++ef) {
                int row = we * 32 + ef * 16 + l15;
                afr[ef] = *(const bf16x8*)(hs + row * 256 + (kb ^ ((row & 15) << 4)));
            }
            #pragma unroll
            for (int ef = 0; ef < 2; ++ef)
                #pragma unroll
                for (int cf = 0; cf < 4; ++cf)
                    acc[ef][cf] = __builtin_amdgcn_mfma_f32_16x16x32_bf16(
                        bfr[cf], afr[ef], acc[ef][cf], 0, 0, 0);
        }
        __syncthreads();   // (C) all hs reads done -> hs reusable as staging

        // ---- transpose epilogue: two 64-edge halves through hs (f32) ----
        // chunk(edge_loc, c4) = edge_loc*32 + (c4 ^ (edge_loc&15))  (bijective,
        // both sides uniform mod 8 -> conflict-free b128)
        #pragma unroll
        for (int hf = 0; hf < 2; ++hf) {
            if ((we >> 1) == hf) {
                const int el_loc = (we & 1) * 32;
                #pragma unroll
                for (int ef = 0; ef < 2; ++ef) {
                    int rloc = el_loc + ef * 16 + l15;
                    #pragma unroll
                    for (int cf = 0; cf < 4; ++cf) {
                        int c4 = wc * 16 + cf * 4 + lq;
                        *(f32x4*)(hs + ((rloc * 32 + (c4 ^ (rloc & 15))) << 4)) =
                            acc[ef][cf];
                    }
                }
            }
            __syncthreads();   // (D) staged

            #pragma unroll
            for (int p = 0; p < 4; ++p) {
                int el_loc = p * 16 + erow;
                int el = hf * 64 + el_loc;
                int e = tile * 128 + el;
                f32x4 v = *(const f32x4*)(hs + ((el_loc * 32 + (c4r ^ (el_loc & 15))) << 4));
                f32x4 q1 = *(const f32x4*)(P1 + xi_s[buf][el] * H + c4r * 4);
                f32x4 q2 = *(const f32x4*)(P2 + xj_s[buf][el] * H + c4r * 4);
                f32x4 o;
                #pragma unroll
                for (int r = 0; r < 4; ++r)
                    o[r] = fast_silu(v[r] + q1[r] + q2[r]);
                if (e < NE)
                    __builtin_nontemporal_store(o, (f32x4*)(out + (size_t)e * H + c4r * 4));
            }
            if (hf == 0) __syncthreads();   // (E) readout0 done before stage1
        }

        // ---- commit next tile into the other buffer ----
        if (hn) {
            int nb = buf ^ 1;
            rbf_s[nb][(tid / 6) * 8 + (tid % 6)] = pr0;
            int d1 = tid + 512;
            if (d1 < 768) rbf_s[nb][(d1 / 6) * 8 + (d1 % 6)] = pr1;
            if (tid < 128) xi_s[nb][tid] = xg;
            else if (tid < 256) xj_s[nb][tid - 128] = xg;
        }
    }
}

extern "C" void kernel_launch(void* const* d_in, const int* in_sizes, int n_in,
                              void* d_out, int out_size, void* d_ws, size_t ws_size,
                              hipStream_t stream) {
    const int*   x      = (const int*)d_in[0];
    const float* rbf    = (const float*)d_in[1];
    const int*   ei     = (const int*)d_in[2];
    const int*   ej     = (const int*)d_in[3];
    const float* emb    = (const float*)d_in[4];
    const float* w_rbf  = (const float*)d_in[5];
    const float* b_rbf  = (const float*)d_in[6];
    const float* w_lin  = (const float*)d_in[7];
    const float* b_lin  = (const float*)d_in[8];
    float* out = (float*)d_out;

    float*    P1  = (float*)d_ws;                 // 95*128 f32
    float*    P2  = P1 + 95 * H;                  // 95*128 f32
    unsigned* w3t = (unsigned*)(P2 + 95 * H);     // 128*64 u32 (bf16 pairs)

    prep_kernel<<<95 + 32, 256, 0, stream>>>(emb, w_lin, b_lin, P1, P2, w3t);

    int nblk = (NTILES + TPB - 1) / TPB;          // 489
    edge_kernel<<<nblk, 512, 0, stream>>>(rbf, ei, ej, x, w_rbf, b_rbf,
                                          P1, P2, w3t, out);
}

// Round 21
// 81.508 us; speedup vs baseline: 1.2113x; 1.2113x over previous
//
#include <hip/hip_runtime.h>
#include <hip/hip_bf16.h>
#include <stdint.h>

#define H 128
#define NE 500000
#define NTILES 3907          // ceil(NE/128)
#define TPB 8                // tiles per block -> 489 blocks (2/CU resident)

typedef __bf16 bf16x8 __attribute__((ext_vector_type(8)));
typedef float f32x4 __attribute__((ext_vector_type(4)));

__device__ __forceinline__ float fast_silu(float x) {
    float e = __builtin_amdgcn_exp2f(x * -1.44269504088896341f);
    return x * __builtin_amdgcn_rcpf(1.0f + e);
}

__device__ __forceinline__ unsigned f2bf(float f) {
    unsigned u = __builtin_bit_cast(unsigned, f);
    return (u + 0x7FFFu + ((u >> 16) & 1u)) >> 16;
}

// ---------------------------------------------------------------------------
// Prep: blocks 0..94:  P1[b][c] = emb[b] @ w_lin[0:128][c] + b_lin[c]
//                      P2[b][c] = emb[b] @ w_lin[128:256][c]
//       blocks 95..126: w3t[c][k] = bf16(w_lin[256+k][c]) packed pairs
// ---------------------------------------------------------------------------
__global__ __launch_bounds__(256)
void prep_kernel(const float* __restrict__ emb,
                 const float* __restrict__ w_lin,
                 const float* __restrict__ b_lin,
                 float* __restrict__ P1, float* __restrict__ P2,
                 unsigned* __restrict__ w3t) {
    int b = blockIdx.x, t = threadIdx.x;
    if (b < 95) {
        __shared__ float emb_s[H];
        if (t < H) emb_s[t] = emb[b * H + t];
        __syncthreads();
        int c = t & (H - 1);
        int half = t >> 7;
        const float* wb = w_lin + half * (H * H) + c;
        float a = half ? 0.0f : b_lin[c];
        #pragma unroll 8
        for (int k = 0; k < H; ++k)
            a = fmaf(emb_s[k], wb[k * H], a);
        (half ? P2 : P1)[b * H + c] = a;
    } else {
        int idx = (b - 95) * 256 + t;
        int c = idx >> 6;
        int k = (idx & 63) * 2;
        unsigned lo = f2bf(w_lin[(2 * H + k) * H + c]);
        unsigned hi = f2bf(w_lin[(2 * H + k + 1) * H + c]);
        w3t[idx] = lo | (hi << 16);
    }
}

// ---------------------------------------------------------------------------
// Main: ROUND 21 = r15 champion restored VERBATIM (82.2us measured).
// The register razor edge (21-experiment ledger): at (512,4) the allocator
// cap is 64 VGPR and r15's working set exactly fits spill-free at 16
// waves/CU. Growing the live set spills (r16-r18: +80-500MB phantom
// traffic); raising the cap via (512,2) balloons allocation past 128 and
// halves occupancy (r19/r20: 95-99us). Structure: 128x128 tile, wl W3^T in
// LDS once/block, h via LDS swizzled, NT stores + full __syncthreads,
// LDS-transpose coalesced epilogue, cvt_pk bf16 casts.
// ---------------------------------------------------------------------------
__global__ __launch_bounds__(512, 4)
void edge_kernel(const float* __restrict__ rbf,
                 const int* __restrict__ ei, const int* __restrict__ ej,
                 const int* __restrict__ xin,
                 const float* __restrict__ w_rbf, const float* __restrict__ b_rbf,
                 const float* __restrict__ P1, const float* __restrict__ P2,
                 const unsigned* __restrict__ w3t,
                 float* __restrict__ out) {
    __shared__ __align__(16) char hs[H * 256];   // h bf16 tile / f32 staging, 32KB
    __shared__ __align__(16) char wl[H * 256];   // W3^T bf16 swizzled, 32KB
    __shared__ float rbf_s[2][128 * 8];          // 2 x 4KB
    __shared__ int xi_s[2][128];
    __shared__ int xj_s[2][128];

    const int tid = threadIdx.x;
    const int wave = tid >> 6;
    const int lane = tid & 63;
    const int we = wave & 3;              // 32-edge group
    const int wc = wave >> 2;             // 64-col group
    const int l15 = lane & 15;
    const int lq = lane >> 4;

    const int tile0 = blockIdx.x * TPB;

    // ---------------- stage W3^T -> LDS once per block (swizzled) ----------
    #pragma unroll
    for (int it = 0; it < 16; ++it) {
        int idx = tid + it * 512;          // 0..8191 ; row c = idx>>6
        int c = idx >> 6;
        int b4 = (idx & 63) * 4;
        *(unsigned*)(wl + c * 256 + (b4 ^ ((c & 15) << 4))) = w3t[idx];
    }

    // ---------------- pipeline registers ----------------
    float pr0 = 0.f, pr1 = 0.f;           // rbf prefetch
    int pidx = 0;                         // raw node index prefetch

    // ---------------- prologue: load + commit tile0 into buf 0 -------------
    {
        long long gb = (long long)tile0 * 768;
        pr0 = (gb + tid < (long long)NE * 6) ? rbf[gb + tid] : 0.f;
        int d1 = tid + 512;
        pr1 = (d1 < 768 && gb + d1 < (long long)NE * 6) ? rbf[gb + d1] : 0.f;
        int e = tile0 * 128 + (tid & 127);
        if (tid < 128)      pidx = (e < NE) ? ei[e] : 0;
        else if (tid < 256) pidx = (e < NE) ? ej[e] : 0;

        int xg = 0;
        if (tid < 256) xg = xin[pidx];
        rbf_s[0][(tid / 6) * 8 + (tid % 6)] = pr0;
        if (tid + 512 < 768) rbf_s[0][((tid + 512) / 6) * 8 + ((tid + 512) % 6)] = pr1;
        if (tid < 128) xi_s[0][tid] = xg;
        else if (tid < 256) xj_s[0][tid - 128] = xg;
    }

    #pragma unroll 1
    for (int t = 0; t < TPB; ++t) {
        const int tile = tile0 + t;
        if (tile >= NTILES) break;
        const int buf = t & 1;
        const bool hn = (t + 1 < TPB) && (tile + 1 < NTILES);

        // ---- issue next tile's global loads early ----
        if (hn) {
            long long gb = (long long)(tile + 1) * 768;
            pr0 = (gb + tid < (long long)NE * 6) ? rbf[gb + tid] : 0.f;
            int d1 = tid + 512;
            pr1 = (d1 < 768 && gb + d1 < (long long)NE * 6) ? rbf[gb + d1] : 0.f;
            int e = (tile + 1) * 128 + (tid & 127);
            if (tid < 128)      pidx = (e < NE) ? ei[e] : 0;
            else if (tid < 256) pidx = (e < NE) ? ej[e] : 0;
        }

        __syncthreads();   // (A) commit visible; hs free (prev readout done)

        // ---- h-phase: thread owns 8 cols x 4 edges ----
        {
            const int c8 = (tid & 15) * 8;
            const int eg = tid >> 4;
            f32x4 w0[6], w1[6];
            #pragma unroll
            for (int k = 0; k < 6; ++k) {
                w0[k] = *(const f32x4*)(w_rbf + k * H + c8);
                w1[k] = *(const f32x4*)(w_rbf + k * H + c8 + 4);
            }
            f32x4 b0 = *(const f32x4*)(b_rbf + c8);
            f32x4 b1 = *(const f32x4*)(b_rbf + c8 + 4);

            #pragma unroll
            for (int i = 0; i < 4; ++i) {
                int el = eg * 4 + i;
                f32x4 r03 = *(const f32x4*)(&rbf_s[buf][el * 8]);
                float2 r45 = *(const float2*)(&rbf_s[buf][el * 8 + 4]);
                float rk[6] = {r03[0], r03[1], r03[2], r03[3], r45.x, r45.y};
                f32x4 s0 = b0, s1 = b1;
                #pragma unroll
                for (int k = 0; k < 6; ++k) {
                    s0 += rk[k] * w0[k];
                    s1 += rk[k] * w1[k];
                }
                // __bf16 casts -> compiler emits v_cvt_pk_bf16_f32 pairs
                bf16x8 hv;
                hv[0] = (__bf16)fast_silu(s0[0]);
                hv[1] = (__bf16)fast_silu(s0[1]);
                hv[2] = (__bf16)fast_silu(s0[2]);
                hv[3] = (__bf16)fast_silu(s0[3]);
                hv[4] = (__bf16)fast_silu(s1[0]);
                hv[5] = (__bf16)fast_silu(s1[1]);
                hv[6] = (__bf16)fast_silu(s1[2]);
                hv[7] = (__bf16)fast_silu(s1[3]);
                *(bf16x8*)(hs + el * 256 + ((c8 * 2) ^ ((el & 15) << 4))) = hv;
            }
        }
        __syncthreads();   // (B) hs (h-tile) ready

        // ---- next tile's xin gather: latency hides under MFMA+epilogue ----
        int xg = 0;
        if (hn && tid < 256) xg = xin[pidx];

        // ---- MFMA: B-fragments from LDS-resident W3^T ----
        f32x4 acc[2][4];
        #pragma unroll
        for (int a = 0; a < 2; ++a)
            #pragma unroll
            for (int b = 0; b < 4; ++b)
                acc[a][b] = (f32x4){0.f, 0.f, 0.f, 0.f};

        #pragma unroll
        for (int ks = 0; ks < 4; ++ks) {
            const int kb = ks * 64 + lq * 16;
            bf16x8 bfr[4];
            #pragma unroll
            for (int cf = 0; cf < 4; ++cf) {
                int c = wc * 64 + cf * 16 + l15;
                bfr[cf] = *(const bf16x8*)(wl + c * 256 + (kb ^ ((c & 15) << 4)));
            }
            bf16x8 afr[2];
            #pragma unroll
            for (int ef = 0; ef < 2; ++ef) {
                int row = we * 32 + ef * 16 + l15;
                afr[ef] = *(const bf16x8*)(hs + row * 256 + (kb ^ ((row & 15) << 4)));
            }
            #pragma unroll
            for (int ef = 0; ef < 2; ++ef)
                #pragma unroll
                for (int cf = 0; cf < 4; ++cf)
                    acc[ef][cf] = __builtin_amdgcn_mfma_f32_16x16x32_bf16(
                        bfr[cf], afr[ef], acc[ef][cf], 0, 0, 0);
        }
        __syncthreads();   // (C) all hs reads done -> hs reusable as staging

        // ---- transpose epilogue: two 64-edge halves through hs (f32) ----
        // chunk(edge_loc, c4) = edge_loc*32 + (c4 ^ (edge_loc&15))  (bijective,
        // both sides uniform mod 8 -> conflict-free b128)
        #pragma unroll
        for (int hf = 0; hf < 2; ++hf) {
            if ((we >> 1) == hf) {
                const int el_loc = (we & 1) * 32;
                #pragma unroll
                for (int ef = 0; ef < 2; ++ef) {
                    int rloc = el_loc + ef * 16 + l15;
                    #pragma unroll
                    for (int cf = 0; cf < 4; ++cf) {
                        int c4 = wc * 16 + cf * 4 + lq;
                        *(f32x4*)(hs + ((rloc * 32 + (c4 ^ (rloc & 15))) << 4)) =
                            acc[ef][cf];
                    }
                }
            }
            __syncthreads();   // (D) staged

            const int c4r = tid & 31;
            #pragma unroll
            for (int p = 0; p < 4; ++p) {
                int el_loc = p * 16 + (tid >> 5);
                int el = hf * 64 + el_loc;
                int e = tile * 128 + el;
                f32x4 v = *(const f32x4*)(hs + ((el_loc * 32 + (c4r ^ (el_loc & 15))) << 4));
                f32x4 q1 = *(const f32x4*)(P1 + xi_s[buf][el] * H + c4r * 4);
                f32x4 q2 = *(const f32x4*)(P2 + xj_s[buf][el] * H + c4r * 4);
                f32x4 o;
                #pragma unroll
                for (int r = 0; r < 4; ++r)
                    o[r] = fast_silu(v[r] + q1[r] + q2[r]);
                if (e < NE)
                    __builtin_nontemporal_store(o, (f32x4*)(out + (size_t)e * H + c4r * 4));
            }
            if (hf == 0) __syncthreads();   // (E) readout0 done before stage1
        }

        // ---- commit next tile into the other buffer ----
        if (hn) {
            int nb = buf ^ 1;
            rbf_s[nb][(tid / 6) * 8 + (tid % 6)] = pr0;
            int d1 = tid + 512;
            if (d1 < 768) rbf_s[nb][(d1 / 6) * 8 + (d1 % 6)] = pr1;
            if (tid < 128) xi_s[nb][tid] = xg;
            else if (tid < 256) xj_s[nb][tid - 128] = xg;
        }
    }
}

extern "C" void kernel_launch(void* const* d_in, const int* in_sizes, int n_in,
                              void* d_out, int out_size, void* d_ws, size_t ws_size,
                              hipStream_t stream) {
    const int*   x      = (const int*)d_in[0];
    const float* rbf    = (const float*)d_in[1];
    const int*   ei     = (const int*)d_in[2];
    const int*   ej     = (const int*)d_in[3];
    const float* emb    = (const float*)d_in[4];
    const float* w_rbf  = (const float*)d_in[5];
    const float* b_rbf  = (const float*)d_in[6];
    const float* w_lin  = (const float*)d_in[7];
    const float* b_lin  = (const float*)d_in[8];
    float* out = (float*)d_out;

    float*    P1  = (float*)d_ws;                 // 95*128 f32
    float*    P2  = P1 + 95 * H;                  // 95*128 f32
    unsigned* w3t = (unsigned*)(P2 + 95 * H);     // 128*64 u32 (bf16 pairs)

    prep_kernel<<<95 + 32, 256, 0, stream>>>(emb, w_lin, b_lin, P1, P2, w3t);

    int nblk = (NTILES + TPB - 1) / TPB;          // 489
    edge_kernel<<<nblk, 512, 0, stream>>>(rbf, ei, ej, x, w_rbf, b_rbf,
                                          P1, P2, w3t, out);
}